// Round 1
// baseline (500.640 us; speedup 1.0000x reference)
//
#include <hip/hip_runtime.h>

// MultiHeadSelfAttention: B=4, S=2048, E=1024, H=16, Dh=64.
// Stage 1: qkv_gemm  -> q,k bf16 head-major [bh][s][d]; V TRANSPOSED [bh][d][s]
// Stage 2: attn      -> swapped-QK^T flash attention, barrier-free, bf16 out
// Stage 3: out_gemm  -> @ Wo^T + bo -> d_out (fp32)

typedef __bf16 bf16;
typedef __attribute__((ext_vector_type(8))) short short8;
typedef __attribute__((ext_vector_type(4))) float floatx4;
typedef __attribute__((ext_vector_type(2))) unsigned int uintx2;

#define MFMA16(a, b, c) __builtin_amdgcn_mfma_f32_16x16x32_bf16((a), (b), (c), 0, 0, 0)

#define LDS_STRIDE 56   // 128x32 tile rows padded 32->56 elems (112 B): 16B-aligned
#define ATT_STRIDE 136  // P rows: 128 cols padded ->136 shorts (272 B): 16B-aligned

__device__ __forceinline__ float fast_exp2(float x) {
    float r;
    asm("v_exp_f32 %0, %1" : "=v"(r) : "v"(x));
    return r;
}
__device__ __forceinline__ unsigned int cvt_pk_bf16(float lo, float hi) {
    unsigned int r;
    asm("v_cvt_pk_bf16_f32 %0, %1, %2" : "=v"(r) : "v"(lo), "v"(hi));
    return r;
}

// 8 contiguous elements -> 8 bf16 (as short8 bit pattern)
__device__ __forceinline__ short8 frag8(const bf16* __restrict__ p) {
    return *(const short8*)p;
}
__device__ __forceinline__ short8 frag8(const float* __restrict__ p) {
    const floatx4 a = *(const floatx4*)p;
    const floatx4 b = *(const floatx4*)(p + 4);
    short8 r;
#pragma unroll
    for (int j = 0; j < 4; j++) {
        r[j]     = __builtin_bit_cast(short, (bf16)a[j]);
        r[4 + j] = __builtin_bit_cast(short, (bf16)b[j]);
    }
    return r;
}

// ---------------------------------------------------------------------------
// 128x128-tile GEMM core: C[m][n] = sum_k A[m][k] * B[n][k]  (both K-contiguous)
// 256 threads = 4 waves (2x2 of 64x64), BK=32, single-buffered LDS.
// ---------------------------------------------------------------------------
template <typename TA, typename TB>
__device__ __forceinline__ void gemm128_core(
    const TA* __restrict__ A, const TB* __restrict__ B, int K,
    int m0, int n0, short* As, short* Bs, floatx4 acc[4][4])
{
    const int tid  = threadIdx.x;
    const int lane = tid & 63;
    const int w    = tid >> 6;
    const int wm   = w >> 1, wn = w & 1;
    const int g    = lane >> 4, c = lane & 15;
    const int lrow = tid >> 2;        // 0..63
    const int lc8  = (tid & 3) * 8;   // 0,8,16,24

#pragma unroll
    for (int mi = 0; mi < 4; mi++)
#pragma unroll
        for (int ni = 0; ni < 4; ni++)
            acc[mi][ni] = (floatx4){0.f, 0.f, 0.f, 0.f};

    for (int k0 = 0; k0 < K; k0 += 32) {
        *(short8*)(As + lrow * LDS_STRIDE + lc8) =
            frag8(A + (size_t)(m0 + lrow) * K + k0 + lc8);
        *(short8*)(As + (lrow + 64) * LDS_STRIDE + lc8) =
            frag8(A + (size_t)(m0 + lrow + 64) * K + k0 + lc8);
        *(short8*)(Bs + lrow * LDS_STRIDE + lc8) =
            frag8(B + (size_t)(n0 + lrow) * K + k0 + lc8);
        *(short8*)(Bs + (lrow + 64) * LDS_STRIDE + lc8) =
            frag8(B + (size_t)(n0 + lrow + 64) * K + k0 + lc8);
        __syncthreads();

        short8 af[4], bfr[4];
#pragma unroll
        for (int mi = 0; mi < 4; mi++)
            af[mi] = *(const short8*)(As + (wm * 64 + mi * 16 + c) * LDS_STRIDE + g * 8);
#pragma unroll
        for (int ni = 0; ni < 4; ni++)
            bfr[ni] = *(const short8*)(Bs + (wn * 64 + ni * 16 + c) * LDS_STRIDE + g * 8);
#pragma unroll
        for (int mi = 0; mi < 4; mi++)
#pragma unroll
            for (int ni = 0; ni < 4; ni++)
                acc[mi][ni] = MFMA16(af[mi], bfr[ni], acc[mi][ni]);
        __syncthreads();
    }
}

// ---------------------------------------------------------------------------
// Stage 1: q/k/v = x @ W{q,k,v}^T + b, scattered to head-major bf16.
// q,k: [bh][s][64].  v: TRANSPOSED [bh][d][2048] so PV's B-operand is
// K-contiguous directly from global (no LDS transpose in stage 2).
// grid (8, 64, 3), block 256
// ---------------------------------------------------------------------------
__global__ __launch_bounds__(256) void qkv_gemm(
    const float* __restrict__ X,
    const float* __restrict__ Wq, const float* __restrict__ Wk, const float* __restrict__ Wv,
    const float* __restrict__ bq, const float* __restrict__ bk, const float* __restrict__ bv,
    bf16* __restrict__ qkv)
{
    __shared__ __align__(16) short As[128 * LDS_STRIDE];
    __shared__ __align__(16) short Bs[128 * LDS_STRIDE];

    const int z = blockIdx.z;
    const float* W    = (z == 0) ? Wq : (z == 1) ? Wk : Wv;
    const float* bias = (z == 0) ? bq : (z == 1) ? bk : bv;
    bf16* outz = qkv + (size_t)z * (8192u * 1024u);

    const int m0 = blockIdx.y * 128;
    const int n0 = blockIdx.x * 128;

    floatx4 acc[4][4];
    gemm128_core(X, W, 1024, m0, n0, As, Bs, acc);

    const int lane = threadIdx.x & 63;
    const int w = threadIdx.x >> 6;
    const int wm = w >> 1, wn = w & 1;
    const int g = lane >> 4, c = lane & 15;

#pragma unroll
    for (int ni = 0; ni < 4; ni++) {
        const int n = n0 + wn * 64 + ni * 16 + c;
        const float bb = bias[n];
        const int h = n >> 6, d = n & 63;
#pragma unroll
        for (int mi = 0; mi < 4; mi++) {
#pragma unroll
            for (int r = 0; r < 4; r++) {
                const int m = m0 + wm * 64 + mi * 16 + g * 4 + r;
                const int b = m >> 11, s = m & 2047;
                const size_t idx = (z == 2)
                    ? ((((size_t)((b << 4) | h)) * 64 + d) * 2048 + s)    // V^T
                    : ((((size_t)((b << 4) | h)) * 2048 + s) * 64 + d);   // Q,K
                outz[idx] = (bf16)(acc[mi][ni][r] + bb);
            }
        }
    }
}

// ---------------------------------------------------------------------------
// Stage 2: flash attention, swapped QK^T, barrier-free. grid (16, 64), block 256.
// Each wave owns 32 queries; K-blocks of 128 keys, online softmax.
//  - S^T = mfma(K, Q): lane (g,c) holds P[key=16ni+4g+r][query=c] -> softmax
//    row stats are 31 lane-local ops + shfl_xor(16/32).
//  - P packed to bf16 via v_cvt_pk_bf16_f32, one ds_write_b64 per 16-key block
//    into a wave-PRIVATE LDS buffer (no __syncthreads anywhere).
//  - PV B-fragments read straight from global V^T (L2-resident).
// ---------------------------------------------------------------------------
__global__ __launch_bounds__(256) void attn_kernel(
    const bf16* __restrict__ qkv, bf16* __restrict__ attn_out)
{
    __shared__ __align__(16) short Pl[4 * 32 * ATT_STRIDE];   // 34.8 KB

    const int bh = blockIdx.y;            // 0..63: b = bh>>4, h = bh&15
    const int q0 = blockIdx.x * 128;
    const size_t HSTRIDE = 2048u * 64u;
    const bf16* __restrict__ Q  = qkv + (size_t)bh * HSTRIDE;
    const bf16* __restrict__ Kp = qkv + 8192u * 1024u + (size_t)bh * HSTRIDE;
    const bf16* __restrict__ Vt = qkv + 2u * 8192u * 1024u + (size_t)bh * HSTRIDE; // [64][2048]

    const int tid  = threadIdx.x;
    const int lane = tid & 63;
    const int w    = tid >> 6;
    const int g    = lane >> 4, c = lane & 15;
    short* __restrict__ Pw = Pl + w * (32 * ATT_STRIDE);

    const float C2 = 0.04508422002778f;  // (1/sqrt(1024)) * log2(e)

    // Q fragments (n = lane&15 = query, k = 8*(lane>>4)+j), resident in regs
    short8 qf[2][2];
#pragma unroll
    for (int qb = 0; qb < 2; qb++)
#pragma unroll
        for (int ks = 0; ks < 2; ks++)
            qf[qb][ks] = *(const short8*)(Q + (size_t)(q0 + w * 32 + qb * 16 + c) * 64
                                            + ks * 32 + g * 8);

    floatx4 o[2][4];
#pragma unroll
    for (int mi = 0; mi < 2; mi++)
#pragma unroll
        for (int di = 0; di < 4; di++)
            o[mi][di] = (floatx4){0.f, 0.f, 0.f, 0.f};
    float m_run[2] = {-1e30f, -1e30f};
    float l_run[2] = {0.f, 0.f};

    for (int kb = 0; kb < 16; kb++) {
        const int k0 = kb * 128;

        // S^T = K Q^T: rows = keys, cols = queries (swapped operands)
        floatx4 sAcc[2][8];
#pragma unroll
        for (int qb = 0; qb < 2; qb++)
#pragma unroll
            for (int ni = 0; ni < 8; ni++)
                sAcc[qb][ni] = (floatx4){0.f, 0.f, 0.f, 0.f};
#pragma unroll
        for (int ks = 0; ks < 2; ks++) {
            short8 kf[8];
#pragma unroll
            for (int ni = 0; ni < 8; ni++)
                kf[ni] = *(const short8*)(Kp + (size_t)(k0 + ni * 16 + c) * 64
                                             + ks * 32 + g * 8);
#pragma unroll
            for (int qb = 0; qb < 2; qb++)
#pragma unroll
                for (int ni = 0; ni < 8; ni++)
                    sAcc[qb][ni] = MFMA16(kf[ni], qf[qb][ks], sAcc[qb][ni]);
        }

        // online softmax: lane (g,c) holds 32 scores of query qb*16+c
        float alpha[2];
#pragma unroll
        for (int qb = 0; qb < 2; qb++) {
            floatx4 mv = sAcc[qb][0];
#pragma unroll
            for (int ni = 1; ni < 8; ni++)
#pragma unroll
                for (int r = 0; r < 4; r++) mv[r] = fmaxf(mv[r], sAcc[qb][ni][r]);
            float mx = fmaxf(fmaxf(mv[0], mv[1]), fmaxf(mv[2], mv[3]));
            mx = fmaxf(mx, __shfl_xor(mx, 16));
            mx = fmaxf(mx, __shfl_xor(mx, 32));
            const float mnew = fmaxf(m_run[qb], mx * C2);
            alpha[qb] = fast_exp2(m_run[qb] - mnew);
            m_run[qb] = mnew;

            floatx4 sv = {0.f, 0.f, 0.f, 0.f};
#pragma unroll
            for (int ni = 0; ni < 8; ni++)
#pragma unroll
                for (int r = 0; r < 4; r++) {
                    const float p = fast_exp2(fmaf(sAcc[qb][ni][r], C2, -mnew));
                    sAcc[qb][ni][r] = p;
                    sv[r] += p;
                }
            float sum = (sv[0] + sv[1]) + (sv[2] + sv[3]);
            sum += __shfl_xor(sum, 16);
            sum += __shfl_xor(sum, 32);
            l_run[qb] = l_run[qb] * alpha[qb] + sum;

            // pack P -> bf16 pairs, one b64 store per 16-key block (wave-private)
#pragma unroll
            for (int ni = 0; ni < 8; ni++) {
                uintx2 pk;
                pk[0] = cvt_pk_bf16(sAcc[qb][ni][0], sAcc[qb][ni][1]);
                pk[1] = cvt_pk_bf16(sAcc[qb][ni][2], sAcc[qb][ni][3]);
                *(uintx2*)(Pw + (qb * 16 + c) * ATT_STRIDE + ni * 16 + g * 4) = pk;
            }
        }

        // rescale O by per-row alpha (O row 4g+r's stats live at lane with c == 4g+r)
#pragma unroll
        for (int mi = 0; mi < 2; mi++)
#pragma unroll
            for (int r = 0; r < 4; r++) {
                const int src = (lane & 48) | (g * 4 + r);
                const float a = __shfl(alpha[mi], src);
#pragma unroll
                for (int di = 0; di < 4; di++) o[mi][di][r] *= a;
            }

        // O += P V   (A = P from wave-private LDS, B = V^T rows from global)
#pragma unroll
        for (int ks2 = 0; ks2 < 4; ks2++) {
            short8 vf[4], pf[2];
#pragma unroll
            for (int di = 0; di < 4; di++)
                vf[di] = *(const short8*)(Vt + (size_t)(di * 16 + c) * 2048
                                             + k0 + ks2 * 32 + g * 8);
#pragma unroll
            for (int mi = 0; mi < 2; mi++)
                pf[mi] = *(const short8*)(Pw + (mi * 16 + c) * ATT_STRIDE + ks2 * 32 + g * 8);
#pragma unroll
            for (int mi = 0; mi < 2; mi++)
#pragma unroll
                for (int di = 0; di < 4; di++)
                    o[mi][di] = MFMA16(pf[mi], vf[di], o[mi][di]);
        }
    }

    // epilogue: O /= l (redistribute l to O's row layout), write bf16
    const int b = bh >> 4, h = bh & 15;
#pragma unroll
    for (int mi = 0; mi < 2; mi++) {
#pragma unroll
        for (int r = 0; r < 4; r++) {
            const int src = (lane & 48) | (g * 4 + r);
            const float linv = 1.0f / __shfl(l_run[mi], src);
            const int srow = q0 + w * 32 + mi * 16 + g * 4 + r;
#pragma unroll
            for (int di = 0; di < 4; di++) {
                attn_out[((size_t)(b * 2048 + srow)) * 1024 + h * 64 + di * 16 + c] =
                    (bf16)(o[mi][di][r] * linv);
            }
        }
    }
}

// ---------------------------------------------------------------------------
// Stage 3: out = attn @ Wo^T + bo -> fp32. grid (8, 64).
// ---------------------------------------------------------------------------
__global__ __launch_bounds__(256) void out_gemm(
    const bf16* __restrict__ A, const float* __restrict__ Wo,
    const float* __restrict__ bo, float* __restrict__ C)
{
    __shared__ __align__(16) short As[128 * LDS_STRIDE];
    __shared__ __align__(16) short Bs[128 * LDS_STRIDE];

    const int m0 = blockIdx.y * 128;
    const int n0 = blockIdx.x * 128;

    floatx4 acc[4][4];
    gemm128_core(A, Wo, 1024, m0, n0, As, Bs, acc);

    const int lane = threadIdx.x & 63;
    const int w = threadIdx.x >> 6;
    const int wm = w >> 1, wn = w & 1;
    const int g = lane >> 4, c = lane & 15;

#pragma unroll
    for (int ni = 0; ni < 4; ni++) {
        const int n = n0 + wn * 64 + ni * 16 + c;
        const float bb = bo[n];
#pragma unroll
        for (int mi = 0; mi < 4; mi++) {
#pragma unroll
            for (int r = 0; r < 4; r++) {
                const int m = m0 + wm * 64 + mi * 16 + g * 4 + r;
                C[(size_t)m * 1024 + n] = acc[mi][ni][r] + bb;
            }
        }
    }
}

// ---------------------------------------------------------------------------
extern "C" void kernel_launch(void* const* d_in, const int* in_sizes, int n_in,
                              void* d_out, int out_size, void* d_ws, size_t ws_size,
                              hipStream_t stream)
{
    const float* x  = (const float*)d_in[0];
    const float* Wq = (const float*)d_in[1];
    const float* bq = (const float*)d_in[2];
    const float* Wk = (const float*)d_in[3];
    const float* bk = (const float*)d_in[4];
    const float* Wv = (const float*)d_in[5];
    const float* bv = (const float*)d_in[6];
    const float* Wo = (const float*)d_in[7];
    const float* bo = (const float*)d_in[8];
    float* out = (float*)d_out;

    bf16* qkv  = (bf16*)d_ws;                       // 3 x 8192x1024 bf16 = 48 MB
    bf16* attn = qkv + 3u * 8192u * 1024u;          // 8192x1024 bf16 = 16 MB

    qkv_gemm<<<dim3(8, 64, 3), dim3(256), 0, stream>>>(x, Wq, Wk, Wv, bq, bk, bv, qkv);
    attn_kernel<<<dim3(16, 64), dim3(256), 0, stream>>>(qkv, attn);
    out_gemm<<<dim3(8, 64), dim3(256), 0, stream>>>(attn, Wo, bo, out);
}